// Round 13
// baseline (44.964 us; speedup 1.0000x reference)
//
#include <hip/hip_runtime.h>
#include <math.h>

// MAM fully-connected: out[r][o] = max_k(x[r][k]*W[o][k]) + min_k(x[r][k]*W[o][k]) + b[o]
// x: (1024, 512) f32, W: (512, 512) f32, b: (512,), out: (1024, 512) f32.
//
// v13: ALL-VMEM K-loop. Diagnosis across R1-R12: every version parked waves
// in waitcnt (VALUBusy 24-38%, nothing saturated). Root cause candidate:
// wave-uniform x scalarizes to s_load, whose UNORDERED lgkmcnt forces full
// lgkmcnt(0) drains every iteration (and mixes with ds_read in LDS versions).
// Here the K-loop touches ONLY vmcnt, in-order, fine-grained:
//  - W read coalesced per-lane from WT (transposed once into d_ws)
//  - x read via VMEM: opaque VGPR zero in the base pointer defeats
//    uniformity analysis (R11-proven); uniform addresses coalesce to 1 line
//  - no LDS, no barrier in the K-loop; single end-merge barrier (16 KB LDS)
//  - wave = 8 rows x 64 outs (lane=out) x K-quarter; 1024 blocks, 16 waves/CU
//  - unroll 2: two iterations of independent loads for vmcnt(N) pipelining
// Budgets/CU: VALU 6.8us, W-L2 3.7us, VMEM-issue 2.5us, DS ~0 -> VALU-bound.

#define K_TOTAL 512
#define O_TOTAL 512
#define OW 64                    // outs per wave (= lanes)
#define RPB 8                    // rows per block (shared by all 4 waves)
#define NQ 4                     // K quarters = waves per block
#define KQ (K_TOTAL / NQ)        // 128

// ---------------- W transpose: WT[k][o] = W[o][k] (R12-proven) ----------------
__global__ __launch_bounds__(256)
void transpose_w(const float* __restrict__ W, float* __restrict__ WT) {
  __shared__ float tile[64][65];
  const int t = threadIdx.x;
  const int ob = blockIdx.x & 7;   // o-tile
  const int kb = blockIdx.x >> 3;  // k-tile
  const int o0 = ob * 64, k0 = kb * 64;
#pragma unroll
  for (int i = 0; i < 4; ++i) {
    const int u = t + 256 * i, r = u >> 4, c = u & 15;
    const float4 v = *reinterpret_cast<const float4*>(W + (size_t)(o0 + r) * K_TOTAL + k0 + c * 4);
    tile[r][c * 4 + 0] = v.x; tile[r][c * 4 + 1] = v.y;
    tile[r][c * 4 + 2] = v.z; tile[r][c * 4 + 3] = v.w;
  }
  __syncthreads();
#pragma unroll
  for (int i = 0; i < 4; ++i) {
    const int u = t + 256 * i, kr = u >> 4, c = u & 15;
    float4 v;
    v.x = tile[c * 4 + 0][kr]; v.y = tile[c * 4 + 1][kr];
    v.z = tile[c * 4 + 2][kr]; v.w = tile[c * 4 + 3][kr];
    *reinterpret_cast<float4*>(WT + (size_t)(k0 + kr) * O_TOTAL + o0 + c * 4) = v;
  }
}

// ---------------- main kernel ----------------
template <bool TRANS>
__global__ __launch_bounds__(256, 4)
void mam_fc_kernel(const float* __restrict__ x, const float* __restrict__ Wm,
                   const float* __restrict__ bias, float* __restrict__ out) {
  __shared__ float red[NQ][RPB][OW][2];   // 16 KB merge buffer

  const int t = threadIdx.x;
  const int lane = t & 63;
  const int q = __builtin_amdgcn_readfirstlane(t >> 6);   // K-quarter
  const int ob = blockIdx.x & 7;        // 8 out-blocks of 64
  const int rg = blockIdx.x >> 3;       // 128 row-groups of 8
  const int o0 = ob * OW;
  const int row0 = rg * RPB;
  const int k0 = q * KQ;

  // ---- x row bases forced onto the VMEM path (opaque VGPR zero) ----
  int vzero;
  asm("v_mov_b32 %0, 0" : "=v"(vzero));
  const float* xrow[RPB];
#pragma unroll
  for (int r = 0; r < RPB; ++r)
    xrow[r] = x + (size_t)(row0 + r) * K_TOTAL + k0 + vzero;

  float amax[RPB], amin[RPB];
#pragma unroll
  for (int r = 0; r < RPB; ++r) { amax[r] = -INFINITY; amin[r] = INFINITY; }

#pragma unroll 2
  for (int kk = 0; kk < KQ; kk += 4) {
    // 4 coalesced W loads (per-lane, 256B each) -- vmcnt, in-order
    float w0, w1, w2, w3;
    if (TRANS) {
      w0 = Wm[(size_t)(k0 + kk + 0) * O_TOTAL + o0 + lane];
      w1 = Wm[(size_t)(k0 + kk + 1) * O_TOTAL + o0 + lane];
      w2 = Wm[(size_t)(k0 + kk + 2) * O_TOTAL + o0 + lane];
      w3 = Wm[(size_t)(k0 + kk + 3) * O_TOTAL + o0 + lane];
    } else {   // fallback (ws too small): strided but correct
      const float* wr = Wm + (size_t)(o0 + lane) * K_TOTAL + k0 + kk;
      w0 = wr[0]; w1 = wr[1]; w2 = wr[2]; w3 = wr[3];
    }
#pragma unroll
    for (int r = 0; r < RPB; ++r) {
      // broadcast float4 (identical per-lane addresses -> 1 line) -- vmcnt
      const float4 xv = *reinterpret_cast<const float4*>(xrow[r] + kk);
      const float p0 = xv.x * w0;
      const float p1 = xv.y * w1;
      const float p2 = xv.z * w2;
      const float p3 = xv.w * w3;
      // 4-deep chains -> 2x v_max3 / 2x v_min3
      amax[r] = fmaxf(fmaxf(fmaxf(fmaxf(amax[r], p0), p1), p2), p3);
      amin[r] = fminf(fminf(fminf(fminf(amin[r], p0), p1), p2), p3);
    }
  }

  // ---- merge the 4 K-quarters (single barrier in the whole kernel) ----
#pragma unroll
  for (int r = 0; r < RPB; ++r) {
    red[q][r][lane][0] = amax[r];
    red[q][r][lane][1] = amin[r];
  }
  __syncthreads();

#pragma unroll
  for (int i = 0; i < 2; ++i) {   // 512 outputs / 256 threads
    const int idx = t + 256 * i;
    const int rr = idx >> 6, oo = idx & 63;
    float m = red[0][rr][oo][0], n = red[0][rr][oo][1];
#pragma unroll
    for (int s = 1; s < NQ; ++s) {
      m = fmaxf(m, red[s][rr][oo][0]);
      n = fminf(n, red[s][rr][oo][1]);
    }
    out[(size_t)(row0 + rr) * O_TOTAL + o0 + oo] = m + n + bias[o0 + oo];
  }
}

extern "C" void kernel_launch(void* const* d_in, const int* in_sizes, int n_in,
                              void* d_out, int out_size, void* d_ws, size_t ws_size,
                              hipStream_t stream) {
  const float* x = (const float*)d_in[0];    // (1024, 512)
  const float* W = (const float*)d_in[1];    // (512, 512)
  const float* b = (const float*)d_in[2];    // (512,)
  float* out = (float*)d_out;                // (1024, 512)

  const int nrows = in_sizes[0] / K_TOTAL;                // 1024
  const int nblocks = (O_TOTAL / OW) * (nrows / RPB);     // 8 * 128 = 1024
  const size_t wt_bytes = (size_t)K_TOTAL * O_TOTAL * sizeof(float);   // 1 MB

  if (ws_size >= wt_bytes) {
    float* WT = (float*)d_ws;
    transpose_w<<<dim3(64), dim3(256), 0, stream>>>(W, WT);
    mam_fc_kernel<true><<<dim3(nblocks), dim3(256), 0, stream>>>(x, WT, b, out);
  } else {
    mam_fc_kernel<false><<<dim3(nblocks), dim3(256), 0, stream>>>(x, W, b, out);
  }
}

// Round 14
// 30.605 us; speedup vs baseline: 1.4692x; 1.4692x over previous
//
#include <hip/hip_runtime.h>
#include <math.h>

// MAM fully-connected: out[r][o] = max_k(x[r][k]*W[o][k]) + min_k(x[r][k]*W[o][k]) + b[o]
// x: (1024, 512) f32, W: (512, 512) f32, b: (512,), out: (1024, 512) f32.
//
// v14: f16 PACKED MATH. 14 f32 structures bottomed at 21-26us: VALU 6.8us +
// one saturated broadcast pipe (K$/DS/TA depending on x path) at ~35% overlap.
// f16 halves both: pk_mul/pk_max/pk_min = 1.5 slots/product (5.1us floor),
// x bytes halve (s_load_dwordx4 per 8 k), W pre-packed WP[kp][o] half2 ->
// one coalesced 4B/lane VMEM load per k-pair. Zero DS / zero barriers in the
// K-loop (single merge barrier). Precision: 3 roundings x 4.9e-4 x |p|<=0.52
// ~= 1.5e-3 worst-case < 6.4e-3 threshold (4x margin).
//  - converts run once into d_ws (1.5 MB): WP 512KB + XH 1MB, ~2us
//  - main: 1024 blocks x 512 thr (8 waves/SIMD, 32 waves/CU), lane=out,
//    wave=K-octant, 8 rows/block; VGPR ~45.

typedef _Float16 h2 __attribute__((ext_vector_type(2)));

#define K_TOTAL 512
#define O_TOTAL 512
#define KP_TOTAL 256             // k-pairs
#define OW 64                    // outs per wave (= lanes)
#define RPB 8                    // rows per block
#define NSEG 8                   // K octants = waves per block
#define KPSEG (KP_TOTAL / NSEG)  // 32 k-pairs per octant

// ---- convert W[o][k] f32 -> WP[kp][o] half2 (read-coalesced) ----
__global__ __launch_bounds__(256)
void conv_w(const float* __restrict__ W, h2* __restrict__ WP) {
  const int tid = blockIdx.x * 256 + threadIdx.x;   // 512*256 = 131072
  const int o = tid >> 8;          // 0..511
  const int kp = tid & 255;        // 0..255
  const float2 v = *reinterpret_cast<const float2*>(W + (size_t)o * K_TOTAL + kp * 2);
  WP[(size_t)kp * O_TOTAL + o] = h2{(_Float16)v.x, (_Float16)v.y};
}

// ---- convert x[r][k] f32 -> XH[r][kp] half2 (fully coalesced) ----
__global__ __launch_bounds__(256)
void conv_x(const float* __restrict__ x, h2* __restrict__ XH, int total) {
  const int tid = blockIdx.x * 256 + threadIdx.x;
  if (tid >= total) return;
  const float2 v = *reinterpret_cast<const float2*>(x + (size_t)tid * 2);
  XH[tid] = h2{(_Float16)v.x, (_Float16)v.y};
}

// ---- main kernel: f16 packed K-loop, no LDS/barriers until the merge ----
__global__ __launch_bounds__(512, 8)
void mam_fc_kernel(const h2* __restrict__ XH, const h2* __restrict__ WP,
                   const float* __restrict__ bias, float* __restrict__ out) {
  __shared__ float red[NSEG][RPB][OW][2];   // 32 KB merge buffer

  const int t = threadIdx.x;
  const int lane = t & 63;
  const int q = __builtin_amdgcn_readfirstlane(t >> 6);   // K-octant
  const int ob = blockIdx.x & 7;        // 8 out-blocks of 64
  const int rg = blockIdx.x >> 3;       // row-groups of 8
  const int o0 = ob * OW;
  const int row0 = rg * RPB;
  const int kp0 = q * KPSEG;

  const h2* xb = XH + (size_t)row0 * KP_TOTAL + kp0;      // uniform -> s_load
  const h2* wb = WP + (size_t)kp0 * O_TOTAL + o0 + lane;  // coalesced per-lane

  h2 amax[RPB], amin[RPB];
#pragma unroll
  for (int r = 0; r < RPB; ++r) {
    amax[r] = h2{(_Float16)(-65504.f), (_Float16)(-65504.f)};  // f16 lowest
    amin[r] = h2{(_Float16)(65504.f), (_Float16)(65504.f)};
  }

#pragma unroll 4
  for (int kp = 0; kp < KPSEG; ++kp) {
    const h2 w2 = wb[(size_t)kp * O_TOTAL];   // 4B/lane, 256B/wave, 2 lines
#pragma unroll
    for (int r = 0; r < RPB; ++r) {
      const h2 x2 = xb[(size_t)r * KP_TOTAL + kp];  // uniform; unroll-4 merges
                                                    // 4 kp -> s_load_dwordx4
      const h2 p = x2 * w2;                               // v_pk_mul_f16
      amax[r] = __builtin_elementwise_max(amax[r], p);    // v_pk_max_f16
      amin[r] = __builtin_elementwise_min(amin[r], p);    // v_pk_min_f16
    }
  }

  // ---- merge the 8 K-octants (single barrier) ----
#pragma unroll
  for (int r = 0; r < RPB; ++r) {
    red[q][r][lane][0] = fmaxf((float)amax[r][0], (float)amax[r][1]);
    red[q][r][lane][1] = fminf((float)amin[r][0], (float)amin[r][1]);
  }
  __syncthreads();

  const int rr = t >> 6;          // 512 threads = 8 rows x 64 outs
  const int oo = t & 63;
  float m = red[0][rr][oo][0], n = red[0][rr][oo][1];
#pragma unroll
  for (int s = 1; s < NSEG; ++s) {
    m = fmaxf(m, red[s][rr][oo][0]);
    n = fminf(n, red[s][rr][oo][1]);
  }
  out[(size_t)(row0 + rr) * O_TOTAL + o0 + oo] = m + n + bias[o0 + oo];
}

// ---- fallback (ws too small): trivially-correct f32 path ----
__global__ __launch_bounds__(256)
void mam_fc_fallback(const float* __restrict__ x, const float* __restrict__ W,
                     const float* __restrict__ bias, float* __restrict__ out,
                     int nrows) {
  const int idx = blockIdx.x * 256 + threadIdx.x;
  if (idx >= nrows * O_TOTAL) return;
  const int r = idx >> 9, o = idx & 511;
  float m = -INFINITY, n = INFINITY;
  for (int k = 0; k < K_TOTAL; ++k) {
    const float p = x[(size_t)r * K_TOTAL + k] * W[(size_t)o * K_TOTAL + k];
    m = fmaxf(m, p);
    n = fminf(n, p);
  }
  out[idx] = m + n + bias[o];
}

extern "C" void kernel_launch(void* const* d_in, const int* in_sizes, int n_in,
                              void* d_out, int out_size, void* d_ws, size_t ws_size,
                              hipStream_t stream) {
  const float* x = (const float*)d_in[0];    // (1024, 512)
  const float* W = (const float*)d_in[1];    // (512, 512)
  const float* b = (const float*)d_in[2];    // (512,)
  float* out = (float*)d_out;                // (1024, 512)

  const int nrows = in_sizes[0] / K_TOTAL;             // 1024
  const int xh_elems = nrows * KP_TOTAL;               // 262144 half2
  const size_t wp_bytes = (size_t)KP_TOTAL * O_TOTAL * sizeof(h2);   // 512 KB
  const size_t xh_bytes = (size_t)xh_elems * sizeof(h2);             // 1 MB

  if (ws_size >= wp_bytes + xh_bytes) {
    h2* WP = (h2*)d_ws;
    h2* XH = (h2*)((char*)d_ws + wp_bytes);
    conv_w<<<dim3(512), dim3(256), 0, stream>>>(W, WP);
    conv_x<<<dim3((xh_elems + 255) / 256), dim3(256), 0, stream>>>(x, XH, xh_elems);
    const int nblocks = (O_TOTAL / OW) * (nrows / RPB);   // 1024
    mam_fc_kernel<<<dim3(nblocks), dim3(512), 0, stream>>>(XH, WP, b, out);
  } else {
    const int nthreads = nrows * O_TOTAL;
    mam_fc_fallback<<<dim3((nthreads + 255) / 256), dim3(256), 0, stream>>>(
        x, W, b, out, nrows);
  }
}

// Round 15
// 27.801 us; speedup vs baseline: 1.6174x; 1.1009x over previous
//
#include <hip/hip_runtime.h>
#include <math.h>

// MAM fully-connected: out[r][o] = max_k(x[r][k]*W[o][k]) + min_k(x[r][k]*W[o][k]) + b[o]
// x: (1024, 512) f32, W: (512, 512) f32, b: (512,), out: (1024, 512) f32.
//
// v15 = v14 (f16 packed main, validated absmax 1.95e-3 < 6.4e-3) with the
// conversion overhead fixed:
//  - conv_w scatter-write bug -> LDS-tiled transpose-convert (coalesced both
//    sides; tile[64][66] 2-way LDS conflicts = free)
//  - conv_w + conv_x FUSED into one kernel (64 + 256 blocks, branch on
//    blockIdx) -> 2 launches total instead of 3
//  - main kernel byte-identical to v14: lane=out, wave=K-octant, 8 rows/blk,
//    512 thr (8 waves/SIMD), zero DS/barriers in K-loop, single 32KB merge;
//    per (kp,r): v_pk_mul_f16 + v_pk_max_f16 + v_pk_min_f16 = 1.5 slots/product

typedef _Float16 h2 __attribute__((ext_vector_type(2)));
typedef _Float16 h8 __attribute__((ext_vector_type(8)));

#define K_TOTAL 512
#define O_TOTAL 512
#define KP_TOTAL 256             // k-pairs
#define OW 64                    // outs per wave (= lanes)
#define RPB 8                    // rows per block
#define NSEG 8                   // K octants = waves per block
#define KPSEG (KP_TOTAL / NSEG)  // 32 k-pairs per octant

// ---- fused convert: blocks [0,64): W transpose-convert; [64,...): x convert ----
__global__ __launch_bounds__(256)
void conv_fused(const float* __restrict__ W, const float* __restrict__ x,
                h2* __restrict__ WP, h2* __restrict__ XH) {
  __shared__ _Float16 tile[64][66];   // 2-way bank alias on read path = free
  const int t = threadIdx.x;

  if (blockIdx.x < 64) {
    // ---- W[o][k] f32 -> WP[kp][o] h2, LDS-tiled (all accesses coalesced) ----
    const int ob = blockIdx.x & 7;    // o-tile
    const int kb = blockIdx.x >> 3;   // k-tile
    const int o0 = ob * 64, k0 = kb * 64;
#pragma unroll
    for (int i = 0; i < 4; ++i) {
      const int u = t + 256 * i, r = u >> 4, c = u & 15;
      const float4 v = *reinterpret_cast<const float4*>(
          W + (size_t)(o0 + r) * K_TOTAL + k0 + c * 4);
      tile[r][c * 4 + 0] = (_Float16)v.x; tile[r][c * 4 + 1] = (_Float16)v.y;
      tile[r][c * 4 + 2] = (_Float16)v.z; tile[r][c * 4 + 3] = (_Float16)v.w;
    }
    __syncthreads();
    const int kp0 = k0 >> 1;
#pragma unroll
    for (int i = 0; i < 8; ++i) {
      const int u = t + 256 * i;          // 0..2047
      const int kpl = u >> 6, ol = u & 63;
      // write: consecutive lanes -> consecutive h2: coalesced 4B/lane
      WP[(size_t)(kp0 + kpl) * O_TOTAL + o0 + ol] =
          h2{tile[ol][2 * kpl], tile[ol][2 * kpl + 1]};
    }
  } else {
    // ---- x f32 -> XH h2, straight through (32B read / 16B write per thread) ----
    const int tid = (blockIdx.x - 64) * 256 + t;
    const float4 a = *reinterpret_cast<const float4*>(x + (size_t)tid * 8);
    const float4 c = *reinterpret_cast<const float4*>(x + (size_t)tid * 8 + 4);
    const h8 v = {(_Float16)a.x, (_Float16)a.y, (_Float16)a.z, (_Float16)a.w,
                  (_Float16)c.x, (_Float16)c.y, (_Float16)c.z, (_Float16)c.w};
    *reinterpret_cast<h8*>(&XH[(size_t)tid * 4]) = v;
  }
}

// ---- main kernel: f16 packed K-loop, no LDS/barriers until the merge ----
__global__ __launch_bounds__(512, 8)
void mam_fc_kernel(const h2* __restrict__ XH, const h2* __restrict__ WP,
                   const float* __restrict__ bias, float* __restrict__ out) {
  __shared__ float red[NSEG][RPB][OW][2];   // 32 KB merge buffer

  const int t = threadIdx.x;
  const int lane = t & 63;
  const int q = __builtin_amdgcn_readfirstlane(t >> 6);   // K-octant
  const int ob = blockIdx.x & 7;        // 8 out-blocks of 64
  const int rg = blockIdx.x >> 3;       // row-groups of 8
  const int o0 = ob * OW;
  const int row0 = rg * RPB;
  const int kp0 = q * KPSEG;

  const h2* xb = XH + (size_t)row0 * KP_TOTAL + kp0;      // uniform -> s_load
  const h2* wb = WP + (size_t)kp0 * O_TOTAL + o0 + lane;  // coalesced per-lane

  h2 amax[RPB], amin[RPB];
#pragma unroll
  for (int r = 0; r < RPB; ++r) {
    amax[r] = h2{(_Float16)(-65504.f), (_Float16)(-65504.f)};
    amin[r] = h2{(_Float16)(65504.f), (_Float16)(65504.f)};
  }

#pragma unroll 4
  for (int kp = 0; kp < KPSEG; ++kp) {
    const h2 w2 = wb[(size_t)kp * O_TOTAL];   // 4B/lane, 256B/wave
#pragma unroll
    for (int r = 0; r < RPB; ++r) {
      const h2 x2 = xb[(size_t)r * KP_TOTAL + kp];  // uniform; unroll-4 ->
                                                    // s_load_dwordx4 batches
      const h2 p = x2 * w2;                               // v_pk_mul_f16
      amax[r] = __builtin_elementwise_max(amax[r], p);    // v_pk_max_f16
      amin[r] = __builtin_elementwise_min(amin[r], p);    // v_pk_min_f16
    }
  }

  // ---- merge the 8 K-octants (single barrier) ----
#pragma unroll
  for (int r = 0; r < RPB; ++r) {
    red[q][r][lane][0] = fmaxf((float)amax[r][0], (float)amax[r][1]);
    red[q][r][lane][1] = fminf((float)amin[r][0], (float)amin[r][1]);
  }
  __syncthreads();

  const int rr = t >> 6;          // 512 threads = 8 rows x 64 outs
  const int oo = t & 63;
  float m = red[0][rr][oo][0], n = red[0][rr][oo][1];
#pragma unroll
  for (int s = 1; s < NSEG; ++s) {
    m = fmaxf(m, red[s][rr][oo][0]);
    n = fminf(n, red[s][rr][oo][1]);
  }
  out[(size_t)(row0 + rr) * O_TOTAL + o0 + oo] = m + n + bias[o0 + oo];
}

// ---- fallback (ws too small): trivially-correct f32 path ----
__global__ __launch_bounds__(256)
void mam_fc_fallback(const float* __restrict__ x, const float* __restrict__ W,
                     const float* __restrict__ bias, float* __restrict__ out,
                     int nrows) {
  const int idx = blockIdx.x * 256 + threadIdx.x;
  if (idx >= nrows * O_TOTAL) return;
  const int r = idx >> 9, o = idx & 511;
  float m = -INFINITY, n = INFINITY;
  for (int k = 0; k < K_TOTAL; ++k) {
    const float p = x[(size_t)r * K_TOTAL + k] * W[(size_t)o * K_TOTAL + k];
    m = fmaxf(m, p);
    n = fminf(n, p);
  }
  out[idx] = m + n + bias[o];
}

extern "C" void kernel_launch(void* const* d_in, const int* in_sizes, int n_in,
                              void* d_out, int out_size, void* d_ws, size_t ws_size,
                              hipStream_t stream) {
  const float* x = (const float*)d_in[0];    // (1024, 512)
  const float* W = (const float*)d_in[1];    // (512, 512)
  const float* b = (const float*)d_in[2];    // (512,)
  float* out = (float*)d_out;                // (1024, 512)

  const int nrows = in_sizes[0] / K_TOTAL;             // 1024
  const size_t wp_bytes = (size_t)KP_TOTAL * O_TOTAL * sizeof(h2);     // 512 KB
  const size_t xh_bytes = (size_t)nrows * KP_TOTAL * sizeof(h2);       // 1 MB

  if (ws_size >= wp_bytes + xh_bytes) {
    h2* WP = (h2*)d_ws;
    h2* XH = (h2*)((char*)d_ws + wp_bytes);
    const int xblocks = in_sizes[0] / (8 * 256);       // 8 floats per thread
    conv_fused<<<dim3(64 + xblocks), dim3(256), 0, stream>>>(W, x, WP, XH);
    const int nblocks = (O_TOTAL / OW) * (nrows / RPB);   // 1024
    mam_fc_kernel<<<dim3(nblocks), dim3(512), 0, stream>>>(XH, WP, b, out);
  } else {
    const int nthreads = nrows * O_TOTAL;
    mam_fc_fallback<<<dim3((nthreads + 255) / 256), dim3(256), 0, stream>>>(
        x, W, b, out, nrows);
  }
}